// Round 2
// baseline (187.520 us; speedup 1.0000x reference)
//
#include <hip/hip_runtime.h>
#include <cstdint>

// B=16384 rows, K=2048 centers, D=128, T=1.0
// Outputs (flat, f32): out[B*D], center[K*D], label[B]
#define NB 16384
#define NK 2048
#define ND 128
#define MARGIN 0.10f
#define CAP 2048
#define XPITCH 132   // padded LDS x-row stride (floats): breaks bank aliasing

typedef __attribute__((ext_vector_type(8))) short bf16x8;
typedef __attribute__((ext_vector_type(4))) float f32x4;
typedef unsigned long long u64;

__device__ __forceinline__ unsigned short f2bf(float f) {
    unsigned u = __float_as_uint(f);
    u += 0x7fffu + ((u >> 16) & 1u);          // round-to-nearest-even
    return (unsigned short)(u >> 16);
}

// ---------------------------------------------------------------------------
// Prep (392 blocks):
//  [0,128)    cbf: center -> bf16 MFMA B-frag layout (identical to R4)
//  [128,136)  c2 (chain identical to R1)
//  [136,392)  center passthrough copy (float4)
// ---------------------------------------------------------------------------
__global__ __launch_bounds__(256)
void prep(const float* __restrict__ c,
          unsigned short* __restrict__ cbf,
          float* __restrict__ c2,
          float* __restrict__ out_center) {
    const int bid = blockIdx.x;
    const int tid = threadIdx.x;
    if (bid < 128) {
        int t = bid * 256 + tid;              // 0..32767
        int lane = t & 63, s = (t >> 6) & 3, kt = t >> 8;
        int kc = kt * 16 + (lane & 15);
        int d0 = s * 32 + (lane >> 4) * 8;
        const float* src = c + (long)kc * ND + d0;
        unsigned short h[8];
#pragma unroll
        for (int j = 0; j < 8; ++j) h[j] = f2bf(src[j]);
        int4 pk;
        pk.x = h[0] | (h[1] << 16); pk.y = h[2] | (h[3] << 16);
        pk.z = h[4] | (h[5] << 16); pk.w = h[6] | (h[7] << 16);
        ((int4*)cbf)[t] = pk;
    } else if (bid < 136) {
        int k = (bid - 128) * 256 + tid;      // 0..2047
        const float4* row = (const float4*)(c + (long)k * ND);
        float s = 0.f;
#pragma unroll 8
        for (int i = 0; i < ND / 4; ++i) {
            float4 v = row[i];
            s += v.x * v.x + v.y * v.y + v.z * v.z + v.w * v.w;
        }
        c2[k] = s;
    } else {
        int i = (bid - 136) * 256 + tid;      // 0..K*D/4-1
        ((float4*)out_center)[i] = ((const float4*)c)[i];
    }
}

// ---------------------------------------------------------------------------
// Main: 512 blocks x 1024 threads (16 waves). Block owns 32 rows x ALL 2048 k
// -> block min IS the global min (no cross-block combine). Wave w covers k in
// [w*128, w*128+128). Two MFMA sweeps (min, then filter) + exact fp32 refine
// with the R1-identical chain; direct out/label writes.
//
// Why 1024 threads: grid is fixed at 512 blocks (32 rows each); at 256
// threads that is 2 blocks/CU = only 2 waves/SIMD, and the serial
// L2-load -> MFMA chain in the ct loop left the machine latency-bound
// (R1: MfmaUtil 12.6%, Occupancy 19.5%). 16 waves/block at the same
// grid = 32 waves/CU = 8 waves/SIMD -> TLP covers the ~300-cycle L2
// latency. __launch_bounds__(1024, 8) pins VGPR <= 64 (R1 used 52).
// ---------------------------------------------------------------------------
__global__ __launch_bounds__(1024, 8)
void kmeans_main(const float* __restrict__ x,
                 const float* __restrict__ center,
                 const unsigned short* __restrict__ cbf,
                 const float* __restrict__ c2,
                 float* __restrict__ out,
                 float* __restrict__ label_out) {
    __shared__ float xs[32 * XPITCH];         // 16.9 KB fp32 x rows
    __shared__ float x2s[32];
    __shared__ unsigned bmin[32];
    __shared__ u64 best[32];
    __shared__ unsigned buf[CAP];             // 8 KB candidate list
    __shared__ unsigned cnt;

    const int tid  = threadIdx.x;
    const int lane = tid & 63;
    const int wave = __builtin_amdgcn_readfirstlane(tid >> 6);  // 0..15
    const long rb  = (long)blockIdx.x * 32;

    // ---- stage x rows -> LDS (coalesced, 1 float4/thread) ----
    {
        int r = tid >> 5, q = tid & 31;
        float4 v = ((const float4*)(x + (rb + r) * ND))[q];
        ((float4*)(xs + r * XPITCH))[q] = v;
    }
    if (tid < 32) { bmin[tid] = 0x7f800000u; best[tid] = ~0ULL; }
    if (tid == 0) cnt = 0;
    __syncthreads();

    // ---- x2 per row: chain IDENTICAL to R1 (float2, 6-level butterfly) ----
    for (int i = 0; i < 2; ++i) {
        int r = wave * 2 + i;
        float2 v = *(const float2*)(xs + r * XPITCH + lane * 2);
        float s = v.x * v.x + v.y * v.y;
#pragma unroll
        for (int off = 32; off; off >>= 1) s += __shfl_xor(s, off, 64);
        if (lane == 0) x2s[r] = s;
    }
    __syncthreads();

    // ---- A-frags into registers (reused by both sweeps) ----
    bf16x8 af[2][4];
#pragma unroll
    for (int rt = 0; rt < 2; ++rt)
#pragma unroll
        for (int s = 0; s < 4; ++s) {
            const float* p = xs + (rt * 16 + (lane & 15)) * XPITCH
                               + s * 32 + (lane >> 4) * 8;
            float4 u0 = ((const float4*)p)[0];
            float4 u1 = ((const float4*)p)[1];
            bf16x8 a;
            a[0] = (short)f2bf(u0.x); a[1] = (short)f2bf(u0.y);
            a[2] = (short)f2bf(u0.z); a[3] = (short)f2bf(u0.w);
            a[4] = (short)f2bf(u1.x); a[5] = (short)f2bf(u1.y);
            a[6] = (short)f2bf(u1.z); a[7] = (short)f2bf(u1.w);
            af[rt][s] = a;
        }

    float x2p[2][4];
#pragma unroll
    for (int rt = 0; rt < 2; ++rt)
#pragma unroll
        for (int reg = 0; reg < 4; ++reg)
            x2p[rt][reg] = x2s[rt * 16 + (lane >> 4) * 4 + reg];

    const bf16x8* CF = (const bf16x8*)cbf;
    const int kbase = wave * 128;

    // ---- sweep 1: min over this wave's 128 k ----
    float rmin[2][4];
#pragma unroll
    for (int rt = 0; rt < 2; ++rt)
#pragma unroll
        for (int reg = 0; reg < 4; ++reg) rmin[rt][reg] = __builtin_inff();

#pragma unroll 2
    for (int ct = 0; ct < 8; ++ct) {
        const int kt = (kbase >> 4) + ct;     // 16-k tile index
        bf16x8 bf[4];
#pragma unroll
        for (int s = 0; s < 4; ++s) bf[s] = CF[(kt * 4 + s) * 64 + lane];
        f32x4 acc0 = {0.f,0.f,0.f,0.f}, acc1 = {0.f,0.f,0.f,0.f};
#pragma unroll
        for (int s = 0; s < 4; ++s) {
            acc0 = __builtin_amdgcn_mfma_f32_16x16x32_bf16(af[0][s], bf[s], acc0, 0,0,0);
            acc1 = __builtin_amdgcn_mfma_f32_16x16x32_bf16(af[1][s], bf[s], acc1, 0,0,0);
        }
        float c2v = c2[kt * 16 + (lane & 15)];
#pragma unroll
        for (int reg = 0; reg < 4; ++reg) {
            rmin[0][reg] = fminf(rmin[0][reg], fmaf(-2.f, acc0[reg], x2p[0][reg] + c2v));
            rmin[1][reg] = fminf(rmin[1][reg], fmaf(-2.f, acc1[reg], x2p[1][reg] + c2v));
        }
    }

    // cross-lane min over the 16 cols (lane&15 group), then block combine
#pragma unroll
    for (int rt = 0; rt < 2; ++rt)
#pragma unroll
        for (int reg = 0; reg < 4; ++reg) {
            float v = rmin[rt][reg];
#pragma unroll
            for (int off = 1; off < 16; off <<= 1)
                v = fminf(v, __shfl_xor(v, off, 64));
            if ((lane & 15) == 0)             // d2a >= 0 -> uint order == float order
                atomicMin(&bmin[rt * 16 + (lane >> 4) * 4 + reg], __float_as_uint(v));
        }
    __syncthreads();

    float thr[2][4];
#pragma unroll
    for (int rt = 0; rt < 2; ++rt)
#pragma unroll
        for (int reg = 0; reg < 4; ++reg)
            thr[rt][reg] = __uint_as_float(bmin[rt * 16 + (lane >> 4) * 4 + reg]) + MARGIN;

    // ---- sweep 2: recompute, filter candidates within MARGIN of block min ----
#pragma unroll 2
    for (int ct = 0; ct < 8; ++ct) {
        const int kt = (kbase >> 4) + ct;
        bf16x8 bf[4];
#pragma unroll
        for (int s = 0; s < 4; ++s) bf[s] = CF[(kt * 4 + s) * 64 + lane];
        f32x4 acc0 = {0.f,0.f,0.f,0.f}, acc1 = {0.f,0.f,0.f,0.f};
#pragma unroll
        for (int s = 0; s < 4; ++s) {
            acc0 = __builtin_amdgcn_mfma_f32_16x16x32_bf16(af[0][s], bf[s], acc0, 0,0,0);
            acc1 = __builtin_amdgcn_mfma_f32_16x16x32_bf16(af[1][s], bf[s], acc1, 0,0,0);
        }
        float c2v = c2[kt * 16 + (lane & 15)];
        const int col = kt * 16 + (lane & 15);
#pragma unroll
        for (int reg = 0; reg < 4; ++reg) {
            float d20 = fmaf(-2.f, acc0[reg], x2p[0][reg] + c2v);
            if (d20 <= thr[0][reg]) {
                unsigned rloc = (lane >> 4) * 4 + reg;          // rt=0
                unsigned idx = atomicAdd(&cnt, 1u);
                if (idx < CAP) buf[idx] = (rloc << 11) | (unsigned)col;
            }
            float d21 = fmaf(-2.f, acc1[reg], x2p[1][reg] + c2v);
            if (d21 <= thr[1][reg]) {
                unsigned rloc = 16 + (lane >> 4) * 4 + reg;     // rt=1
                unsigned idx = atomicAdd(&cnt, 1u);
                if (idx < CAP) buf[idx] = (rloc << 11) | (unsigned)col;
            }
        }
    }
    __syncthreads();

    // ---- exact refine: fp32 chain IDENTICAL to R1 (serial fmaf dot,
    //      t=x2+c2, fmaf(-2,dot,t), max, sqrt; u64 key -> lowest k on tie) ----
    unsigned n = cnt; if (n > CAP) n = CAP;
    for (unsigned i = tid; i < n; i += 1024) {
        unsigned pc = buf[i];
        int rloc = pc >> 11, col = pc & (NK - 1);
        const float* xr = xs + rloc * XPITCH;
        const float* cr = center + (long)col * ND;
        float dot = 0.f;
#pragma unroll 8
        for (int d = 0; d < ND; ++d) dot = fmaf(xr[d], cr[d], dot);
        float t = x2s[rloc] + c2[col];
        float f = fmaxf(fmaf(-2.0f, dot, t), 0.0f);
        float s = __builtin_sqrtf(f);
        u64 key = ((u64)__float_as_uint(s) << 32) | (unsigned)col;
        atomicMin(&best[rloc], key);
    }
    __syncthreads();

    // ---- direct output: gather center[bk] per row + label ----
    for (int i = 0; i < 2; ++i) {
        int rloc = wave * 2 + i;
        int bk = (int)(best[rloc] & 0xffffffffULL);
        float2 cv = ((const float2*)(center + (long)bk * ND))[lane];
        ((float2*)(out + (rb + rloc) * ND))[lane] = cv;
        if (lane == 0) label_out[rb + rloc] = (float)bk;
    }
}

// ---------------------------------------------------------------------------
extern "C" void kernel_launch(void* const* d_in, const int* in_sizes, int n_in,
                              void* d_out, int out_size, void* d_ws, size_t ws_size,
                              hipStream_t stream) {
    const float* x      = (const float*)d_in[0];   // [B][D]
    const float* center = (const float*)d_in[1];   // [K][D]
    float* out = (float*)d_out;

    float* out_x      = out;                        // [B*D]
    float* out_center = out + (long)NB * ND;        // [K*D]
    float* out_label  = out_center + (long)NK * ND; // [B]

    // Workspace: cbf[K*D]u16 (0.5MB), c2[K]f32
    unsigned short* cbf = (unsigned short*)d_ws;
    float* c2 = (float*)(cbf + (size_t)NK * ND);

    prep<<<392, 256, 0, stream>>>(center, cbf, c2, out_center);
    kmeans_main<<<NB / 32, 1024, 0, stream>>>(x, center, cbf, c2,
                                              out_x, out_label);
}

// Round 3
// 97.675 us; speedup vs baseline: 1.9198x; 1.9198x over previous
//
#include <hip/hip_runtime.h>
#include <cstdint>

// B=16384 rows, K=2048 centers, D=128, T=1.0
// Outputs (flat, f32): out[B*D], center[K*D], label[B]
#define NB 16384
#define NK 2048
#define ND 128
#define MARGIN 0.10f
#define CAP 2048
#define XPITCH 132   // padded LDS x-row stride (floats): breaks bank aliasing

typedef __attribute__((ext_vector_type(8))) short bf16x8;
typedef __attribute__((ext_vector_type(4))) float f32x4;
typedef unsigned long long u64;

__device__ __forceinline__ unsigned short f2bf(float f) {
    unsigned u = __float_as_uint(f);
    u += 0x7fffu + ((u >> 16) & 1u);          // round-to-nearest-even
    return (unsigned short)(u >> 16);
}

// ---------------------------------------------------------------------------
// Prep (392 blocks):
//  [0,128)    cbf: center -> bf16 MFMA B-frag layout (identical to R4)
//  [128,136)  c2 (chain identical to R1)
//  [136,392)  center passthrough copy (float4)
// ---------------------------------------------------------------------------
__global__ __launch_bounds__(256)
void prep(const float* __restrict__ c,
          unsigned short* __restrict__ cbf,
          float* __restrict__ c2,
          float* __restrict__ out_center) {
    const int bid = blockIdx.x;
    const int tid = threadIdx.x;
    if (bid < 128) {
        int t = bid * 256 + tid;              // 0..32767
        int lane = t & 63, s = (t >> 6) & 3, kt = t >> 8;
        int kc = kt * 16 + (lane & 15);
        int d0 = s * 32 + (lane >> 4) * 8;
        const float* src = c + (long)kc * ND + d0;
        unsigned short h[8];
#pragma unroll
        for (int j = 0; j < 8; ++j) h[j] = f2bf(src[j]);
        int4 pk;
        pk.x = h[0] | (h[1] << 16); pk.y = h[2] | (h[3] << 16);
        pk.z = h[4] | (h[5] << 16); pk.w = h[6] | (h[7] << 16);
        ((int4*)cbf)[t] = pk;
    } else if (bid < 136) {
        int k = (bid - 128) * 256 + tid;      // 0..2047
        const float4* row = (const float4*)(c + (long)k * ND);
        float s = 0.f;
#pragma unroll 8
        for (int i = 0; i < ND / 4; ++i) {
            float4 v = row[i];
            s += v.x * v.x + v.y * v.y + v.z * v.z + v.w * v.w;
        }
        c2[k] = s;
    } else {
        int i = (bid - 136) * 256 + tid;      // 0..K*D/4-1
        ((float4*)out_center)[i] = ((const float4*)c)[i];
    }
}

// ---------------------------------------------------------------------------
// Main: 512 blocks x 512 threads (8 waves). Block owns 32 rows x ALL 2048 k
// -> block min IS the global min (no cross-block combine). Wave w covers k in
// [w*256, w*256+256). Two MFMA sweeps (min, then filter) + exact fp32 refine
// with the R1-identical chain; direct out/label writes.
//
// Occupancy history:
//  R1: 256 thr, (256,2)  -> 2 waves/SIMD, latency-bound, 49 us, MfmaUtil 13%.
//  R2: 1024 thr, (1024,8) -> forced <=64 VGPR bin, compiler hit 32 VGPR and
//      SPILLED (FETCH 188 MB scratch traffic), 131 us. 8 waves/SIMD is
//      unreachable for this ~90-reg live set.
//  R3: 512 thr, (512,4)  -> 2 blocks/CU x 8 waves = 4 waves/SIMD at the
//      128-VGPR bin: enough TLP to cover ~300-cyc L2 latency, no spills.
// ---------------------------------------------------------------------------
__global__ __launch_bounds__(512, 4)
void kmeans_main(const float* __restrict__ x,
                 const float* __restrict__ center,
                 const unsigned short* __restrict__ cbf,
                 const float* __restrict__ c2,
                 float* __restrict__ out,
                 float* __restrict__ label_out) {
    __shared__ float xs[32 * XPITCH];         // 16.9 KB fp32 x rows
    __shared__ float x2s[32];
    __shared__ unsigned bmin[32];
    __shared__ u64 best[32];
    __shared__ unsigned buf[CAP];             // 8 KB candidate list
    __shared__ unsigned cnt;

    const int tid  = threadIdx.x;
    const int lane = tid & 63;
    const int wave = __builtin_amdgcn_readfirstlane(tid >> 6);  // 0..7
    const long rb  = (long)blockIdx.x * 32;

    // ---- stage x rows -> LDS (coalesced, 2 float4/thread) ----
    {
        int idx = tid;                        // float4 index 0..1023
        int r = idx >> 5, q = idx & 31;
        ((float4*)(xs + r * XPITCH))[q] = ((const float4*)(x + (rb + r) * ND))[q];
        idx = tid + 512;
        r = idx >> 5; q = idx & 31;
        ((float4*)(xs + r * XPITCH))[q] = ((const float4*)(x + (rb + r) * ND))[q];
    }
    if (tid < 32) { bmin[tid] = 0x7f800000u; best[tid] = ~0ULL; }
    if (tid == 0) cnt = 0;
    __syncthreads();

    // ---- x2 per row: chain IDENTICAL to R1 (float2, 6-level butterfly) ----
    for (int i = 0; i < 4; ++i) {
        int r = wave * 4 + i;
        float2 v = *(const float2*)(xs + r * XPITCH + lane * 2);
        float s = v.x * v.x + v.y * v.y;
#pragma unroll
        for (int off = 32; off; off >>= 1) s += __shfl_xor(s, off, 64);
        if (lane == 0) x2s[r] = s;
    }
    __syncthreads();

    // ---- A-frags into registers (reused by both sweeps) ----
    bf16x8 af[2][4];
#pragma unroll
    for (int rt = 0; rt < 2; ++rt)
#pragma unroll
        for (int s = 0; s < 4; ++s) {
            const float* p = xs + (rt * 16 + (lane & 15)) * XPITCH
                               + s * 32 + (lane >> 4) * 8;
            float4 u0 = ((const float4*)p)[0];
            float4 u1 = ((const float4*)p)[1];
            bf16x8 a;
            a[0] = (short)f2bf(u0.x); a[1] = (short)f2bf(u0.y);
            a[2] = (short)f2bf(u0.z); a[3] = (short)f2bf(u0.w);
            a[4] = (short)f2bf(u1.x); a[5] = (short)f2bf(u1.y);
            a[6] = (short)f2bf(u1.z); a[7] = (short)f2bf(u1.w);
            af[rt][s] = a;
        }

    float x2p[2][4];
#pragma unroll
    for (int rt = 0; rt < 2; ++rt)
#pragma unroll
        for (int reg = 0; reg < 4; ++reg)
            x2p[rt][reg] = x2s[rt * 16 + (lane >> 4) * 4 + reg];

    const bf16x8* CF = (const bf16x8*)cbf;
    const int kbase = wave * 256;

    // ---- sweep 1: min over this wave's 256 k ----
    float rmin[2][4];
#pragma unroll
    for (int rt = 0; rt < 2; ++rt)
#pragma unroll
        for (int reg = 0; reg < 4; ++reg) rmin[rt][reg] = __builtin_inff();

#pragma unroll 2
    for (int ct = 0; ct < 16; ++ct) {
        const int kt = (kbase >> 4) + ct;     // 16-k tile index
        bf16x8 bf[4];
#pragma unroll
        for (int s = 0; s < 4; ++s) bf[s] = CF[(kt * 4 + s) * 64 + lane];
        f32x4 acc0 = {0.f,0.f,0.f,0.f}, acc1 = {0.f,0.f,0.f,0.f};
#pragma unroll
        for (int s = 0; s < 4; ++s) {
            acc0 = __builtin_amdgcn_mfma_f32_16x16x32_bf16(af[0][s], bf[s], acc0, 0,0,0);
            acc1 = __builtin_amdgcn_mfma_f32_16x16x32_bf16(af[1][s], bf[s], acc1, 0,0,0);
        }
        float c2v = c2[kt * 16 + (lane & 15)];
#pragma unroll
        for (int reg = 0; reg < 4; ++reg) {
            rmin[0][reg] = fminf(rmin[0][reg], fmaf(-2.f, acc0[reg], x2p[0][reg] + c2v));
            rmin[1][reg] = fminf(rmin[1][reg], fmaf(-2.f, acc1[reg], x2p[1][reg] + c2v));
        }
    }

    // cross-lane min over the 16 cols (lane&15 group), then block combine
#pragma unroll
    for (int rt = 0; rt < 2; ++rt)
#pragma unroll
        for (int reg = 0; reg < 4; ++reg) {
            float v = rmin[rt][reg];
#pragma unroll
            for (int off = 1; off < 16; off <<= 1)
                v = fminf(v, __shfl_xor(v, off, 64));
            if ((lane & 15) == 0)             // d2a >= 0 -> uint order == float order
                atomicMin(&bmin[rt * 16 + (lane >> 4) * 4 + reg], __float_as_uint(v));
        }
    __syncthreads();

    float thr[2][4];
#pragma unroll
    for (int rt = 0; rt < 2; ++rt)
#pragma unroll
        for (int reg = 0; reg < 4; ++reg)
            thr[rt][reg] = __uint_as_float(bmin[rt * 16 + (lane >> 4) * 4 + reg]) + MARGIN;

    // ---- sweep 2: recompute, filter candidates within MARGIN of block min ----
#pragma unroll 2
    for (int ct = 0; ct < 16; ++ct) {
        const int kt = (kbase >> 4) + ct;
        bf16x8 bf[4];
#pragma unroll
        for (int s = 0; s < 4; ++s) bf[s] = CF[(kt * 4 + s) * 64 + lane];
        f32x4 acc0 = {0.f,0.f,0.f,0.f}, acc1 = {0.f,0.f,0.f,0.f};
#pragma unroll
        for (int s = 0; s < 4; ++s) {
            acc0 = __builtin_amdgcn_mfma_f32_16x16x32_bf16(af[0][s], bf[s], acc0, 0,0,0);
            acc1 = __builtin_amdgcn_mfma_f32_16x16x32_bf16(af[1][s], bf[s], acc1, 0,0,0);
        }
        float c2v = c2[kt * 16 + (lane & 15)];
        const int col = kt * 16 + (lane & 15);
#pragma unroll
        for (int reg = 0; reg < 4; ++reg) {
            float d20 = fmaf(-2.f, acc0[reg], x2p[0][reg] + c2v);
            if (d20 <= thr[0][reg]) {
                unsigned rloc = (lane >> 4) * 4 + reg;          // rt=0
                unsigned idx = atomicAdd(&cnt, 1u);
                if (idx < CAP) buf[idx] = (rloc << 11) | (unsigned)col;
            }
            float d21 = fmaf(-2.f, acc1[reg], x2p[1][reg] + c2v);
            if (d21 <= thr[1][reg]) {
                unsigned rloc = 16 + (lane >> 4) * 4 + reg;     // rt=1
                unsigned idx = atomicAdd(&cnt, 1u);
                if (idx < CAP) buf[idx] = (rloc << 11) | (unsigned)col;
            }
        }
    }
    __syncthreads();

    // ---- exact refine: fp32 chain IDENTICAL to R1 (serial fmaf dot,
    //      t=x2+c2, fmaf(-2,dot,t), max, sqrt; u64 key -> lowest k on tie) ----
    unsigned n = cnt; if (n > CAP) n = CAP;
    for (unsigned i = tid; i < n; i += 512) {
        unsigned pc = buf[i];
        int rloc = pc >> 11, col = pc & (NK - 1);
        const float* xr = xs + rloc * XPITCH;
        const float* cr = center + (long)col * ND;
        float dot = 0.f;
#pragma unroll 8
        for (int d = 0; d < ND; ++d) dot = fmaf(xr[d], cr[d], dot);
        float t = x2s[rloc] + c2[col];
        float f = fmaxf(fmaf(-2.0f, dot, t), 0.0f);
        float s = __builtin_sqrtf(f);
        u64 key = ((u64)__float_as_uint(s) << 32) | (unsigned)col;
        atomicMin(&best[rloc], key);
    }
    __syncthreads();

    // ---- direct output: gather center[bk] per row + label ----
    for (int i = 0; i < 4; ++i) {
        int rloc = wave * 4 + i;
        int bk = (int)(best[rloc] & 0xffffffffULL);
        float2 cv = ((const float2*)(center + (long)bk * ND))[lane];
        ((float2*)(out + (rb + rloc) * ND))[lane] = cv;
        if (lane == 0) label_out[rb + rloc] = (float)bk;
    }
}

// ---------------------------------------------------------------------------
extern "C" void kernel_launch(void* const* d_in, const int* in_sizes, int n_in,
                              void* d_out, int out_size, void* d_ws, size_t ws_size,
                              hipStream_t stream) {
    const float* x      = (const float*)d_in[0];   // [B][D]
    const float* center = (const float*)d_in[1];   // [K][D]
    float* out = (float*)d_out;

    float* out_x      = out;                        // [B*D]
    float* out_center = out + (long)NB * ND;        // [K*D]
    float* out_label  = out_center + (long)NK * ND; // [B]

    // Workspace: cbf[K*D]u16 (0.5MB), c2[K]f32
    unsigned short* cbf = (unsigned short*)d_ws;
    float* c2 = (float*)(cbf + (size_t)NK * ND);

    prep<<<392, 256, 0, stream>>>(center, cbf, c2, out_center);
    kmeans_main<<<NB / 32, 512, 0, stream>>>(x, center, cbf, c2,
                                             out_x, out_label);
}

// Round 4
// 96.216 us; speedup vs baseline: 1.9490x; 1.0152x over previous
//
#include <hip/hip_runtime.h>
#include <cstdint>

// B=16384 rows, K=2048 centers, D=128, T=1.0
// Outputs (flat, f32): out[B*D], center[K*D], label[B]
#define NB 16384
#define NK 2048
#define ND 128
#define MARGIN 0.10f
#define CAP 2048
#define XPITCH 132   // padded LDS x-row stride (floats): breaks bank aliasing

typedef __attribute__((ext_vector_type(8))) short bf16x8;
typedef __attribute__((ext_vector_type(4))) float f32x4;
typedef unsigned long long u64;

__device__ __forceinline__ unsigned short f2bf(float f) {
    unsigned u = __float_as_uint(f);
    u += 0x7fffu + ((u >> 16) & 1u);          // round-to-nearest-even
    return (unsigned short)(u >> 16);
}

// ---------------------------------------------------------------------------
// Prep (392 blocks):
//  [0,128)    cbf: center -> bf16 MFMA B-frag layout (identical to R4)
//  [128,136)  c2 (chain identical to R1)
//  [136,392)  center passthrough copy (float4)
// ---------------------------------------------------------------------------
__global__ __launch_bounds__(256)
void prep(const float* __restrict__ c,
          unsigned short* __restrict__ cbf,
          float* __restrict__ c2,
          float* __restrict__ out_center) {
    const int bid = blockIdx.x;
    const int tid = threadIdx.x;
    if (bid < 128) {
        int t = bid * 256 + tid;              // 0..32767
        int lane = t & 63, s = (t >> 6) & 3, kt = t >> 8;
        int kc = kt * 16 + (lane & 15);
        int d0 = s * 32 + (lane >> 4) * 8;
        const float* src = c + (long)kc * ND + d0;
        unsigned short h[8];
#pragma unroll
        for (int j = 0; j < 8; ++j) h[j] = f2bf(src[j]);
        int4 pk;
        pk.x = h[0] | (h[1] << 16); pk.y = h[2] | (h[3] << 16);
        pk.z = h[4] | (h[5] << 16); pk.w = h[6] | (h[7] << 16);
        ((int4*)cbf)[t] = pk;
    } else if (bid < 136) {
        int k = (bid - 128) * 256 + tid;      // 0..2047
        const float4* row = (const float4*)(c + (long)k * ND);
        float s = 0.f;
#pragma unroll 8
        for (int i = 0; i < ND / 4; ++i) {
            float4 v = row[i];
            s += v.x * v.x + v.y * v.y + v.z * v.z + v.w * v.w;
        }
        c2[k] = s;
    } else {
        int i = (bid - 136) * 256 + tid;      // 0..K*D/4-1
        ((float4*)out_center)[i] = ((const float4*)c)[i];
    }
}

// ---------------------------------------------------------------------------
// Main: 512 blocks x 512 threads (8 waves). Block owns 32 rows x ALL 2048 k
// -> block min IS the global min (no cross-block combine). Wave w covers k in
// [w*256, w*256+256). Two MFMA sweeps (min, then filter) + exact fp32 refine
// with the R1-identical chain; direct out/label writes.
//
// History:
//  R1: (256,2)  2 waves/SIMD, latency-bound, 49 us, MfmaUtil 13%.
//  R2: (1024,8) forced <=64 VGPR, spilled (188 MB scratch), 131 us.
//  R3: (512,4)  4 waves/SIMD, ~38 us. Pipes still <15% busy -> the ct loop
//      serializes on same-iteration load->waitcnt->MFMA chains.
//  R4: manual 1-deep B-frag prefetch (compute on frags loaded LAST iter,
//      next tile's loads in flight across the MFMA block) + c2 staged to
//      LDS (kills the odd per-iter 4B global load polluting vmcnt).
//      #pragma unroll 1 pins VGPR under the 128 cap (2 blocks/CU resident).
// ---------------------------------------------------------------------------
__global__ __launch_bounds__(512, 4)
void kmeans_main(const float* __restrict__ x,
                 const float* __restrict__ center,
                 const unsigned short* __restrict__ cbf,
                 const float* __restrict__ c2,
                 float* __restrict__ out,
                 float* __restrict__ label_out) {
    __shared__ float xs[32 * XPITCH];         // 16.9 KB fp32 x rows
    __shared__ float c2s[NK];                 // 8 KB center norms
    __shared__ float x2s[32];
    __shared__ unsigned bmin[32];
    __shared__ u64 best[32];
    __shared__ unsigned buf[CAP];             // 8 KB candidate list
    __shared__ unsigned cnt;

    const int tid  = threadIdx.x;
    const int lane = tid & 63;
    const int wave = __builtin_amdgcn_readfirstlane(tid >> 6);  // 0..7
    const long rb  = (long)blockIdx.x * 32;

    // ---- stage x rows -> LDS (coalesced, 2 float4/thread) ----
    {
        int idx = tid;                        // float4 index 0..1023
        int r = idx >> 5, q = idx & 31;
        ((float4*)(xs + r * XPITCH))[q] = ((const float4*)(x + (rb + r) * ND))[q];
        idx = tid + 512;
        r = idx >> 5; q = idx & 31;
        ((float4*)(xs + r * XPITCH))[q] = ((const float4*)(x + (rb + r) * ND))[q];
    }
    // ---- stage c2 -> LDS (4 floats/thread, coalesced) ----
    ((float4*)c2s)[tid] = ((const float4*)c2)[tid];
    if (tid < 32) { bmin[tid] = 0x7f800000u; best[tid] = ~0ULL; }
    if (tid == 0) cnt = 0;
    __syncthreads();

    // ---- x2 per row: chain IDENTICAL to R1 (float2, 6-level butterfly) ----
    for (int i = 0; i < 4; ++i) {
        int r = wave * 4 + i;
        float2 v = *(const float2*)(xs + r * XPITCH + lane * 2);
        float s = v.x * v.x + v.y * v.y;
#pragma unroll
        for (int off = 32; off; off >>= 1) s += __shfl_xor(s, off, 64);
        if (lane == 0) x2s[r] = s;
    }
    __syncthreads();

    // ---- A-frags into registers (reused by both sweeps) ----
    bf16x8 af[2][4];
#pragma unroll
    for (int rt = 0; rt < 2; ++rt)
#pragma unroll
        for (int s = 0; s < 4; ++s) {
            const float* p = xs + (rt * 16 + (lane & 15)) * XPITCH
                               + s * 32 + (lane >> 4) * 8;
            float4 u0 = ((const float4*)p)[0];
            float4 u1 = ((const float4*)p)[1];
            bf16x8 a;
            a[0] = (short)f2bf(u0.x); a[1] = (short)f2bf(u0.y);
            a[2] = (short)f2bf(u0.z); a[3] = (short)f2bf(u0.w);
            a[4] = (short)f2bf(u1.x); a[5] = (short)f2bf(u1.y);
            a[6] = (short)f2bf(u1.z); a[7] = (short)f2bf(u1.w);
            af[rt][s] = a;
        }

    float x2p[2][4];
#pragma unroll
    for (int rt = 0; rt < 2; ++rt)
#pragma unroll
        for (int reg = 0; reg < 4; ++reg)
            x2p[rt][reg] = x2s[rt * 16 + (lane >> 4) * 4 + reg];

    const bf16x8* CF = (const bf16x8*)cbf;
    const int kbase = wave * 256;
    const int kt0   = kbase >> 4;

    // ---- sweep 1: min over this wave's 256 k (1-deep B-frag prefetch) ----
    float rmin[2][4];
#pragma unroll
    for (int rt = 0; rt < 2; ++rt)
#pragma unroll
        for (int reg = 0; reg < 4; ++reg) rmin[rt][reg] = __builtin_inff();

    {
        bf16x8 b0 = CF[(kt0 * 4 + 0) * 64 + lane];
        bf16x8 b1 = CF[(kt0 * 4 + 1) * 64 + lane];
        bf16x8 b2 = CF[(kt0 * 4 + 2) * 64 + lane];
        bf16x8 b3 = CF[(kt0 * 4 + 3) * 64 + lane];
#pragma unroll 1
        for (int ct = 0; ct < 16; ++ct) {
            const int kt  = kt0 + ct;
            const int ktn = kt0 + ((ct + 1) & 15);      // wraps; last iter reloads tile 0 (unused)
            bf16x8 n0 = CF[(ktn * 4 + 0) * 64 + lane];
            bf16x8 n1 = CF[(ktn * 4 + 1) * 64 + lane];
            bf16x8 n2 = CF[(ktn * 4 + 2) * 64 + lane];
            bf16x8 n3 = CF[(ktn * 4 + 3) * 64 + lane];
            f32x4 acc0 = {0.f,0.f,0.f,0.f}, acc1 = {0.f,0.f,0.f,0.f};
            acc0 = __builtin_amdgcn_mfma_f32_16x16x32_bf16(af[0][0], b0, acc0, 0,0,0);
            acc1 = __builtin_amdgcn_mfma_f32_16x16x32_bf16(af[1][0], b0, acc1, 0,0,0);
            acc0 = __builtin_amdgcn_mfma_f32_16x16x32_bf16(af[0][1], b1, acc0, 0,0,0);
            acc1 = __builtin_amdgcn_mfma_f32_16x16x32_bf16(af[1][1], b1, acc1, 0,0,0);
            acc0 = __builtin_amdgcn_mfma_f32_16x16x32_bf16(af[0][2], b2, acc0, 0,0,0);
            acc1 = __builtin_amdgcn_mfma_f32_16x16x32_bf16(af[1][2], b2, acc1, 0,0,0);
            acc0 = __builtin_amdgcn_mfma_f32_16x16x32_bf16(af[0][3], b3, acc0, 0,0,0);
            acc1 = __builtin_amdgcn_mfma_f32_16x16x32_bf16(af[1][3], b3, acc1, 0,0,0);
            float c2v = c2s[kt * 16 + (lane & 15)];
#pragma unroll
            for (int reg = 0; reg < 4; ++reg) {
                rmin[0][reg] = fminf(rmin[0][reg], fmaf(-2.f, acc0[reg], x2p[0][reg] + c2v));
                rmin[1][reg] = fminf(rmin[1][reg], fmaf(-2.f, acc1[reg], x2p[1][reg] + c2v));
            }
            b0 = n0; b1 = n1; b2 = n2; b3 = n3;
        }
    }

    // cross-lane min over the 16 cols (lane&15 group), then block combine
#pragma unroll
    for (int rt = 0; rt < 2; ++rt)
#pragma unroll
        for (int reg = 0; reg < 4; ++reg) {
            float v = rmin[rt][reg];
#pragma unroll
            for (int off = 1; off < 16; off <<= 1)
                v = fminf(v, __shfl_xor(v, off, 64));
            if ((lane & 15) == 0)             // d2a >= 0 -> uint order == float order
                atomicMin(&bmin[rt * 16 + (lane >> 4) * 4 + reg], __float_as_uint(v));
        }
    __syncthreads();

    float thr[2][4];
#pragma unroll
    for (int rt = 0; rt < 2; ++rt)
#pragma unroll
        for (int reg = 0; reg < 4; ++reg)
            thr[rt][reg] = __uint_as_float(bmin[rt * 16 + (lane >> 4) * 4 + reg]) + MARGIN;

    // ---- sweep 2: recompute, filter candidates within MARGIN of block min ----
    {
        bf16x8 b0 = CF[(kt0 * 4 + 0) * 64 + lane];
        bf16x8 b1 = CF[(kt0 * 4 + 1) * 64 + lane];
        bf16x8 b2 = CF[(kt0 * 4 + 2) * 64 + lane];
        bf16x8 b3 = CF[(kt0 * 4 + 3) * 64 + lane];
#pragma unroll 1
        for (int ct = 0; ct < 16; ++ct) {
            const int kt  = kt0 + ct;
            const int ktn = kt0 + ((ct + 1) & 15);
            bf16x8 n0 = CF[(ktn * 4 + 0) * 64 + lane];
            bf16x8 n1 = CF[(ktn * 4 + 1) * 64 + lane];
            bf16x8 n2 = CF[(ktn * 4 + 2) * 64 + lane];
            bf16x8 n3 = CF[(ktn * 4 + 3) * 64 + lane];
            f32x4 acc0 = {0.f,0.f,0.f,0.f}, acc1 = {0.f,0.f,0.f,0.f};
            acc0 = __builtin_amdgcn_mfma_f32_16x16x32_bf16(af[0][0], b0, acc0, 0,0,0);
            acc1 = __builtin_amdgcn_mfma_f32_16x16x32_bf16(af[1][0], b0, acc1, 0,0,0);
            acc0 = __builtin_amdgcn_mfma_f32_16x16x32_bf16(af[0][1], b1, acc0, 0,0,0);
            acc1 = __builtin_amdgcn_mfma_f32_16x16x32_bf16(af[1][1], b1, acc1, 0,0,0);
            acc0 = __builtin_amdgcn_mfma_f32_16x16x32_bf16(af[0][2], b2, acc0, 0,0,0);
            acc1 = __builtin_amdgcn_mfma_f32_16x16x32_bf16(af[1][2], b2, acc1, 0,0,0);
            acc0 = __builtin_amdgcn_mfma_f32_16x16x32_bf16(af[0][3], b3, acc0, 0,0,0);
            acc1 = __builtin_amdgcn_mfma_f32_16x16x32_bf16(af[1][3], b3, acc1, 0,0,0);
            float c2v = c2s[kt * 16 + (lane & 15)];
            const int col = kt * 16 + (lane & 15);
#pragma unroll
            for (int reg = 0; reg < 4; ++reg) {
                float d20 = fmaf(-2.f, acc0[reg], x2p[0][reg] + c2v);
                if (d20 <= thr[0][reg]) {
                    unsigned rloc = (lane >> 4) * 4 + reg;          // rt=0
                    unsigned idx = atomicAdd(&cnt, 1u);
                    if (idx < CAP) buf[idx] = (rloc << 11) | (unsigned)col;
                }
                float d21 = fmaf(-2.f, acc1[reg], x2p[1][reg] + c2v);
                if (d21 <= thr[1][reg]) {
                    unsigned rloc = 16 + (lane >> 4) * 4 + reg;     // rt=1
                    unsigned idx = atomicAdd(&cnt, 1u);
                    if (idx < CAP) buf[idx] = (rloc << 11) | (unsigned)col;
                }
            }
            b0 = n0; b1 = n1; b2 = n2; b3 = n3;
        }
    }
    __syncthreads();

    // ---- exact refine: fp32 chain IDENTICAL to R1 (serial fmaf dot,
    //      t=x2+c2, fmaf(-2,dot,t), max, sqrt; u64 key -> lowest k on tie) ----
    unsigned n = cnt; if (n > CAP) n = CAP;
    for (unsigned i = tid; i < n; i += 512) {
        unsigned pc = buf[i];
        int rloc = pc >> 11, col = pc & (NK - 1);
        const float* xr = xs + rloc * XPITCH;
        const float* cr = center + (long)col * ND;
        float dot = 0.f;
#pragma unroll 8
        for (int d = 0; d < ND; ++d) dot = fmaf(xr[d], cr[d], dot);
        float t = x2s[rloc] + c2s[col];
        float f = fmaxf(fmaf(-2.0f, dot, t), 0.0f);
        float s = __builtin_sqrtf(f);
        u64 key = ((u64)__float_as_uint(s) << 32) | (unsigned)col;
        atomicMin(&best[rloc], key);
    }
    __syncthreads();

    // ---- direct output: gather center[bk] per row + label ----
    for (int i = 0; i < 4; ++i) {
        int rloc = wave * 4 + i;
        int bk = (int)(best[rloc] & 0xffffffffULL);
        float2 cv = ((const float2*)(center + (long)bk * ND))[lane];
        ((float2*)(out + (rb + rloc) * ND))[lane] = cv;
        if (lane == 0) label_out[rb + rloc] = (float)bk;
    }
}

// ---------------------------------------------------------------------------
extern "C" void kernel_launch(void* const* d_in, const int* in_sizes, int n_in,
                              void* d_out, int out_size, void* d_ws, size_t ws_size,
                              hipStream_t stream) {
    const float* x      = (const float*)d_in[0];   // [B][D]
    const float* center = (const float*)d_in[1];   // [K][D]
    float* out = (float*)d_out;

    float* out_x      = out;                        // [B*D]
    float* out_center = out + (long)NB * ND;        // [K*D]
    float* out_label  = out_center + (long)NK * ND; // [B]

    // Workspace: cbf[K*D]u16 (0.5MB), c2[K]f32
    unsigned short* cbf = (unsigned short*)d_ws;
    float* c2 = (float*)(cbf + (size_t)NK * ND);

    prep<<<392, 256, 0, stream>>>(center, cbf, c2, out_center);
    kmeans_main<<<NB / 32, 512, 0, stream>>>(x, center, cbf, c2,
                                             out_x, out_label);
}